// Round 10
// baseline (745.786 us; speedup 1.0000x reference)
//
#include <hip/hip_runtime.h>
#include <hip/hip_fp16.h>

typedef _Float16 f16;
typedef _Float16 f16x8 __attribute__((ext_vector_type(8)));
typedef float f32x4 __attribute__((ext_vector_type(4)));
typedef int int4v __attribute__((ext_vector_type(4)));

#define BM 128
#define BN 128
#define NBUF 3
#define BUFSZ 16384              // A 8KB + B 8KB (int8, K-tile = 64)

typedef const __attribute__((address_space(1))) unsigned int* gas_ptr;
typedef __attribute__((address_space(3))) unsigned int* las_ptr;

__device__ __forceinline__ void gload_lds16(const void* g, void* l) {
    __builtin_amdgcn_global_load_lds((gas_ptr)g, (las_ptr)l, 16, 0, 0);
}

// ---------------------------------------------------------------------------
// Pre-pass 1: per-row int8 quantization of xs = x/smooth.
// Outputs: Aq[M][K] int8, sx[M] f32, U[M][32] f16 (per-group sums of xs)
// ---------------------------------------------------------------------------
__global__ __launch_bounds__(256) void quantx_kernel(
    const float* __restrict__ x, const float* __restrict__ smooth,
    char* __restrict__ Aq, float* __restrict__ sx, f16* __restrict__ U,
    int M, int K)
{
    const int row = blockIdx.x * 4 + (threadIdx.x >> 6);
    const int lane = threadIdx.x & 63;
    if (row >= M) return;

    f32x4 xsv[16];
    float amax = 0.f;
#pragma unroll
    for (int j = 0; j < 16; ++j) {
        const int k = j * 256 + lane * 4;
        const f32x4 xv = *(const f32x4*)(x + (size_t)row * K + k);
        const f32x4 sv = *(const f32x4*)(smooth + k);
        f32x4 r;
#pragma unroll
        for (int e = 0; e < 4; ++e) {
            r[e] = xv[e] / sv[e];
            amax = fmaxf(amax, fabsf(r[e]));
        }
        xsv[j] = r;
    }
#pragma unroll
    for (int off = 1; off < 64; off <<= 1)
        amax = fmaxf(amax, __shfl_xor(amax, off));
    const float sxr = fmaxf(amax, 1e-20f) / 127.f;
    const float inv = 127.f / fmaxf(amax, 1e-20f);
    if (lane == 0) sx[row] = sxr;

    int* aq32 = (int*)(Aq + (size_t)row * K);
#pragma unroll
    for (int j = 0; j < 16; ++j) {
        unsigned int pk = 0;
        float s4 = 0.f;
#pragma unroll
        for (int e = 0; e < 4; ++e) {
            const float v = xsv[j][e];
            s4 += v;
            int qi = (int)__builtin_rintf(v * inv);
            qi = qi > 127 ? 127 : (qi < -127 ? -127 : qi);
            pk |= ((unsigned int)(qi & 255)) << (8 * e);
        }
        aq32[j * 64 + lane] = (int)pk;
#pragma unroll
        for (int off = 1; off < 32; off <<= 1)
            s4 += __shfl_xor(s4, off);
        if ((lane & 31) == 0)
            U[(size_t)row * 32 + 2 * j + (lane >> 5)] = (f16)s4;
    }
}

// ---------------------------------------------------------------------------
// Pre-pass 2: unpack int32-per-byte nibbles -> Wq[N][K] int8 (q-8, exact).
// ---------------------------------------------------------------------------
__global__ __launch_bounds__(256) void repackw_kernel(
    const int* __restrict__ packed, char* __restrict__ Wq, int total8)
{
    const int i = blockIdx.x * 256 + threadIdx.x;
    if (i >= total8) return;
    const int4v p0 = *(const int4v*)(packed + i * 8);
    const int4v p1 = *(const int4v*)(packed + i * 8 + 4);
    int4v o;
#pragma unroll
    for (int w = 0; w < 4; ++w) {
        const int a = (w < 2) ? p0[2 * w] : p1[2 * (w - 2)];
        const int b = (w < 2) ? p0[2 * w + 1] : p1[2 * (w - 2) + 1];
        const int l0 = ((a & 15) - 8) & 255, h0 = (((a >> 4) & 15) - 8) & 255;
        const int l1 = ((b & 15) - 8) & 255, h1 = (((b >> 4) & 15) - 8) & 255;
        o[w] = l0 | (h0 << 8) | (l1 << 16) | (h1 << 24);
    }
    *(int4v*)(Wq + (size_t)i * 16) = o;
}

// ---------------------------------------------------------------------------
// Pre-pass 3: Vneg[N][32] f16 = -wscale[g][n] * wzero[g][n]
// ---------------------------------------------------------------------------
__global__ __launch_bounds__(256) void vneg_kernel(
    const float* __restrict__ wscale, const float* __restrict__ wzero,
    f16* __restrict__ Vneg, int N)
{
    const int i = blockIdx.x * 256 + threadIdx.x;
    if (i >= N * 32) return;
    const int n = i >> 5;
    const int g = i & 31;
    Vneg[i] = (f16)(-wscale[(size_t)g * N + n] * wzero[(size_t)g * N + n]);
}

// ---------------------------------------------------------------------------
// GEMM (i8 MFMA), occupancy build: 128x128 tile, 4 waves (2x2, wave 64x64,
// acc=64 VGPR), NBUF=3 (48KB LDS) -> 3 blocks/CU (12 waves, 3/SIMD).
// Per K-64 tile: stage T+2 into buffer (T-1) [race-free: read during T-1,
// retired at T-1's end barrier]; read 8 frags; 16 MFMA + fixup; one
// vmcnt(0)+barrier (all outstanding loads aged >= 1 full tile).
// r9-proven staging geometry / XOR swizzle (0 conflicts) / epilogue scheme.
// ---------------------------------------------------------------------------
__global__ __launch_bounds__(256, 3) void gemm_kernel(
    const char* __restrict__ Aq,       // [M][K] int8
    const char* __restrict__ Wq,       // [N][K] int8
    const float* __restrict__ wscale,  // [32][N] f32
    const float* __restrict__ sx,      // [M] f32
    const f16* __restrict__ U,         // [M][32] f16
    const f16* __restrict__ Vneg,      // [N][32] f16
    const float* __restrict__ bias,    // [N]
    float* __restrict__ C,             // [M][N] f32
    int M, int N, int K)
{
    __shared__ char lds[NBUF * BUFSZ];   // 48 KiB

    const int t = threadIdx.x;
    const int lane = t & 63;
    const int wid = t >> 6;
    const int wr = wid >> 1;          // 0..1 (M half)
    const int wc = wid & 1;           // 0..1 (N half)
    const int fr = lane & 15;
    const int fq = lane >> 4;

    const int nbm = M / BM;           // 64
    const int nbn = N / BN;           // 86
    const int nwg = nbm * nbn;        // 5504, %8 == 0
    const int bid = (int)blockIdx.x;
    const int cpx = nwg >> 3;
    const int wg = ((nwg & 7) == 0) ? ((bid & 7) * cpx + (bid >> 3)) : bid;
    const int bm = wg % nbm;          // bm-major: consecutive wg share B panel
    const int bn = wg / nbm;
    const size_t m0 = (size_t)bm * BM;
    const size_t n0 = (size_t)bn * BN;

    // ---- staging geometry (256 threads, 4KB per gload; r9-verified map) ----
    const int scv = (t & 7) ^ ((t >> 3) & 7);
    const int rbase = 2 * (t >> 3) + (scv >> 2);   // 0..63
    const int kb = (scv & 3) * 16;                 // byte offset in 64B row
    const char* gAq = Aq + (m0 + rbase) * (size_t)K + kb;
    const char* gWq = Wq + (n0 + rbase) * (size_t)K + kb;

#define STAGE_AB(sb, Tst) do { char* _d = lds + (sb) + t * 16; \
    gload_lds16(gAq + (size_t)(Tst) * 64, _d); \
    gload_lds16(gAq + (size_t)64 * K + (size_t)(Tst) * 64, _d + 4096); \
    gload_lds16(gWq + (size_t)(Tst) * 64, _d + 8192); \
    gload_lds16(gWq + (size_t)64 * K + (size_t)(Tst) * 64, _d + 12288); } while (0)

    // ---- ds_read lane constants (r9-proven swizzle) ----
    const int aswz = ((((fr & 1) << 2) | fq) ^ ((fr >> 1) & 7)) << 4;
    const int aBase = wr * 4096 + ((fr >> 1) << 7) + aswz;
    const int bBase = 8192 + wc * 4096 + ((fr >> 1) << 7) + aswz;

#define LDA(db, m) (*(const int4v*)(lds + (db) + aBase + (m) * 1024))
#define LDB(db, n) (*(const int4v*)(lds + (db) + bBase + (n) * 1024))

    f32x4 accf[4][4];
#pragma unroll
    for (int m = 0; m < 4; ++m)
#pragma unroll
        for (int n = 0; n < 4; ++n)
            accf[m][n] = {0.f, 0.f, 0.f, 0.f};

    const int4v kz = {0, 0, 0, 0};
    const int NT = K >> 6;            // 64 K-tiles; group = T>>1

    // ---- prologue: stage tiles 0,1; load group-0 scales ----
    STAGE_AB(0, 0);
    STAGE_AB(BUFSZ, 1);
    float sgc[4], sgn[4];
#pragma unroll
    for (int n = 0; n < 4; ++n)
        sgc[n] = wscale[n0 + wc * 64 + n * 16 + fr];
    asm volatile("s_waitcnt vmcnt(0)" ::: "memory");
    __builtin_amdgcn_s_barrier();

#pragma unroll 1
    for (int T = 0; T < NT; ++T) {
        const int db = (T % 3) * BUFSZ;
        const int sb = ((T + 2) % 3) * BUFSZ;

        // ---- issue next+1 tile's stages (land in the retired buffer) ----
        if (T + 2 < NT) STAGE_AB(sb, T + 2);
        // ---- prefetch next group's scales during odd tiles ----
        if ((T & 1) && (T >> 1) + 1 < 32) {
#pragma unroll
            for (int n = 0; n < 4; ++n)
                sgn[n] = wscale[(size_t)((T >> 1) + 1) * N + n0 + wc * 64 + n * 16 + fr];
        }

        // ---- read B frags (cached across m), stream A ----
        int4v bfr[4];
#pragma unroll
        for (int n = 0; n < 4; ++n) bfr[n] = LDB(db, n);

        __builtin_amdgcn_s_setprio(1);
#pragma unroll
        for (int m = 0; m < 4; ++m) {
            const int4v av = LDA(db, m);
#pragma unroll
            for (int n = 0; n < 4; ++n) {
                const int4v tv = __builtin_amdgcn_mfma_i32_16x16x64_i8(
                    av, bfr[n], kz, 0, 0, 0);
#pragma unroll
                for (int e = 0; e < 4; ++e)
                    accf[m][n][e] += sgc[n] * (float)tv[e];
            }
        }
        __builtin_amdgcn_s_setprio(0);

        if (T & 1) {
#pragma unroll
            for (int n = 0; n < 4; ++n) sgc[n] = sgn[n];
        }

        // ---- single tile-boundary sync (loads aged >= 1 tile) ----
        asm volatile("s_waitcnt vmcnt(0)" ::: "memory");
        __builtin_amdgcn_s_barrier();
    }

    // ---- epilogue 1: scale by per-row sx ----
#pragma unroll
    for (int m = 0; m < 4; ++m) {
        const f32x4 sxv = *(const f32x4*)(sx + m0 + wr * 64 + m * 16 + fq * 4);
#pragma unroll
        for (int n = 0; n < 4; ++n)
#pragma unroll
            for (int e = 0; e < 4; ++e)
                accf[m][n][e] *= sxv[e];
    }

    // ---- epilogue 2: rank-32 zero-point correction via f16 MFMA ----
    {
        f16x8 uf[4], vf[4];
#pragma unroll
        for (int m = 0; m < 4; ++m)
            uf[m] = *(const f16x8*)(U + (m0 + wr * 64 + m * 16 + fr) * 32 + fq * 8);
#pragma unroll
        for (int n = 0; n < 4; ++n)
            vf[n] = *(const f16x8*)(Vneg + (n0 + wc * 64 + n * 16 + fr) * 32 + fq * 8);
#pragma unroll
        for (int m = 0; m < 4; ++m)
#pragma unroll
            for (int n = 0; n < 4; ++n)
                accf[m][n] = __builtin_amdgcn_mfma_f32_16x16x32_f16(
                    uf[m], vf[n], accf[m][n], 0, 0, 0);
    }

    // ---- epilogue 3: + bias, f32 scatter stores (static indices) ----
#pragma unroll
    for (int n = 0; n < 4; ++n) {
        const size_t gcol = n0 + wc * 64 + n * 16 + fr;
        const float bv = bias[gcol];
#pragma unroll
        for (int am = 0; am < 4; ++am) {
            const size_t grow = m0 + wr * 64 + am * 16 + fq * 4;
#pragma unroll
            for (int r = 0; r < 4; ++r)
                C[(grow + r) * N + gcol] = accf[am][n][r] + bv;
        }
    }
}

extern "C" void kernel_launch(void* const* d_in, const int* in_sizes, int n_in,
                              void* d_out, int out_size, void* d_ws, size_t ws_size,
                              hipStream_t stream) {
    const float* x      = (const float*)d_in[0];
    const int* packed   = (const int*)d_in[1];
    const float* wscale = (const float*)d_in[2];
    const float* wzero  = (const float*)d_in[3];
    const float* smooth = (const float*)d_in[4];
    const float* bias   = (const float*)d_in[5];
    float* out = (float*)d_out;

    const int K = in_sizes[4];             // 4096
    const int N = in_sizes[5];             // 11008
    const int M = in_sizes[0] / K;         // 8192
    const size_t MK = (size_t)M * K;
    const size_t NK = (size_t)N * K;

    char* Aq  = (char*)d_ws;
    char* Wq  = Aq + MK;
    f16* U    = (f16*)(Wq + NK);
    f16* Vneg = U + (size_t)M * 32;
    float* sxp = (float*)(Vneg + (size_t)N * 32);

    quantx_kernel<<<(M + 3) / 4, 256, 0, stream>>>(x, smooth, Aq, sxp, U, M, K);
    const int total8 = (int)(NK / 16);
    repackw_kernel<<<(total8 + 255) / 256, 256, 0, stream>>>(packed, Wq, total8);
    vneg_kernel<<<(N * 32 + 255) / 256, 256, 0, stream>>>(wscale, wzero, Vneg, N);

    const int grid_gemm = (M / BM) * (N / BN);
    gemm_kernel<<<grid_gemm, 256, 0, stream>>>(
        Aq, Wq, wscale, sxp, U, Vneg, bias, out, M, N, K);
}